// Round 3
// baseline (283.548 us; speedup 1.0000x reference)
//
#include <hip/hip_runtime.h>

// MaskedEmbedding: out[t, :] = (mask_real[x[t], :] > THR ? weight[x[t], :] : 0)
// x: [B*S] int32, mask_real/weight: [VOCAB, D] fp32, out: [B*S, D] fp32.
//
// Latency-oriented layout: 4 tokens per 192-thread block.
//  - one s_load_dwordx4 pulls all 4 (contiguous, block-uniform) indices
//  - 8 independent global_load_dwordx4 per lane in flight (Little's law)
//  - nontemporal stores: output is write-once, keep L2 for gather-row reuse
//
// Note: __builtin_nontemporal_store requires a native Clang vector type,
// not HIP_vector_type — use ext_vector_type(4) throughout.

typedef float f32x4 __attribute__((ext_vector_type(4)));

#define D_DIM 768
#define D4 (D_DIM / 4)       // 192 float4 per row
#define THR 0.01f
#define TPB 4                // tokens per block

__global__ __launch_bounds__(D4) void masked_embedding_kernel(
    const int* __restrict__ x,
    const f32x4* __restrict__ mask,
    const f32x4* __restrict__ weight,
    f32x4* __restrict__ out,
    int n_tokens)
{
    const int col = threadIdx.x;            // 0 .. 191
    const int t0  = blockIdx.x * TPB;

    // Block-uniform contiguous indices -> scalar dwordx4 load.
    int rows[TPB];
#pragma unroll
    for (int i = 0; i < TPB; ++i)
        rows[i] = x[t0 + i];

    // Issue all 8 vector loads before any use.
    f32x4 m[TPB], w[TPB];
#pragma unroll
    for (int i = 0; i < TPB; ++i) {
        const size_t src = (size_t)rows[i] * D4 + col;
        m[i] = mask[src];
        w[i] = weight[src];
    }

#pragma unroll
    for (int i = 0; i < TPB; ++i) {
        f32x4 o;
        o.x = (m[i].x > THR) ? w[i].x : 0.0f;
        o.y = (m[i].y > THR) ? w[i].y : 0.0f;
        o.z = (m[i].z > THR) ? w[i].z : 0.0f;
        o.w = (m[i].w > THR) ? w[i].w : 0.0f;
        __builtin_nontemporal_store(o, &out[(size_t)(t0 + i) * D4 + col]);
    }
}

extern "C" void kernel_launch(void* const* d_in, const int* in_sizes, int n_in,
                              void* d_out, int out_size, void* d_ws, size_t ws_size,
                              hipStream_t stream)
{
    const int*   x      = (const int*)d_in[0];     // [B*S]
    const f32x4* mask   = (const f32x4*)d_in[1];   // [VOCAB, D]
    const f32x4* weight = (const f32x4*)d_in[2];   // [VOCAB, D]
    f32x4*       out    = (f32x4*)d_out;           // [B*S, D]

    const int n_tokens = in_sizes[0];              // B*S = 16384 (divisible by TPB)
    const int n_blocks = n_tokens / TPB;

    masked_embedding_kernel<<<n_blocks, D4, 0, stream>>>(x, mask, weight, out, n_tokens);
}

// Round 4
// 282.500 us; speedup vs baseline: 1.0037x; 1.0037x over previous
//
#include <hip/hip_runtime.h>

// MaskedEmbedding: out[t, :] = (mask_real[x[t], :] > THR ? weight[x[t], :] : 0)
// x: [B*S] int32, mask_real/weight: [VOCAB, D] fp32, out: [B*S, D] fp32.
//
// Wave-per-token grid-stride version (discriminating experiment R3):
//  - one wave owns a token; lane covers 3 chunks of 64 f32x4 (768 floats)
//  - 2 tokens per iteration -> 12 independent global_load_dwordx4 in flight
//  - wave-uniform row index -> scalar load path
//  - nontemporal stores: output is write-once, keep L2 for gather-row reuse

typedef float f32x4 __attribute__((ext_vector_type(4)));

#define D_DIM  768
#define D4     (D_DIM / 4)   // 192 f32x4 per row
#define CHUNKS 3             // 192 / 64 lanes
#define THR    0.01f
#define TPW    2             // tokens per wave-iteration

__global__ __launch_bounds__(256, 4) void masked_embedding_kernel(
    const int* __restrict__ x,
    const f32x4* __restrict__ mask,
    const f32x4* __restrict__ weight,
    f32x4* __restrict__ out,
    int n_tokens)
{
    const int lane   = threadIdx.x & 63;
    const int gwave  = (int)((blockIdx.x * blockDim.x + threadIdx.x) >> 6);
    const int nwaves = (int)((gridDim.x * blockDim.x) >> 6);

    for (int t0 = gwave * TPW; t0 < n_tokens; t0 += nwaves * TPW) {
        // Wave-uniform indices -> s_load.
        int rows[TPW];
#pragma unroll
        for (int i = 0; i < TPW; ++i)
            rows[i] = x[t0 + i];

        // Issue all 12 vector loads before any use.
        f32x4 m[TPW][CHUNKS], w[TPW][CHUNKS];
#pragma unroll
        for (int i = 0; i < TPW; ++i) {
            const size_t base = (size_t)rows[i] * D4 + lane;
#pragma unroll
            for (int c = 0; c < CHUNKS; ++c) {
                m[i][c] = mask[base + 64 * c];
                w[i][c] = weight[base + 64 * c];
            }
        }

#pragma unroll
        for (int i = 0; i < TPW; ++i) {
            const size_t obase = (size_t)(t0 + i) * D4 + lane;
#pragma unroll
            for (int c = 0; c < CHUNKS; ++c) {
                f32x4 o;
                o.x = (m[i][c].x > THR) ? w[i][c].x : 0.0f;
                o.y = (m[i][c].y > THR) ? w[i][c].y : 0.0f;
                o.z = (m[i][c].z > THR) ? w[i][c].z : 0.0f;
                o.w = (m[i][c].w > THR) ? w[i][c].w : 0.0f;
                __builtin_nontemporal_store(o, &out[obase + 64 * c]);
            }
        }
    }
}

extern "C" void kernel_launch(void* const* d_in, const int* in_sizes, int n_in,
                              void* d_out, int out_size, void* d_ws, size_t ws_size,
                              hipStream_t stream)
{
    const int*   x      = (const int*)d_in[0];     // [B*S]
    const f32x4* mask   = (const f32x4*)d_in[1];   // [VOCAB, D]
    const f32x4* weight = (const f32x4*)d_in[2];   // [VOCAB, D]
    f32x4*       out    = (f32x4*)d_out;           // [B*S, D]

    const int n_tokens = in_sizes[0];              // B*S = 16384 (divisible by TPW)

    // 2048 blocks * 4 waves = 8192 waves = n_tokens / TPW -> one iteration/wave.
    const int n_blocks = (n_tokens / TPW + 4 - 1) / 4;  // 4 waves per 256-thread block

    masked_embedding_kernel<<<n_blocks, 256, 0, stream>>>(x, mask, weight, out, n_tokens);
}